// Round 2
// baseline (334.910 us; speedup 1.0000x reference)
//
#include <hip/hip_runtime.h>
#include <hip/hip_bf16.h>
#include <math.h>

// Problem constants
#define BB   32
#define HH   40
#define WW   256
#define NF   40          // FREQ
#define H1N  36
#define W1N  252
#define KCNN 580608      // 64*36*252
#define KPW  192         // k per wave (6 chunks x 32); 3024 waves * 192 == KCNN exactly
#define NBLK2 756        // k2 grid

typedef __attribute__((ext_vector_type(8))) short bf16x8;   // 8 bf16 = 4 VGPRs
typedef __attribute__((ext_vector_type(4))) float f32x4;    // MFMA C/D

static __device__ __forceinline__ unsigned short f2bf(float v) {
    __hip_bfloat16 h = __float2bfloat16(v);
    return *(unsigned short*)&h;
}

static __device__ __forceinline__ bf16x8 packbf(float4 lo, float4 hi) {
    bf16x8 r;
    r[0] = (short)f2bf(lo.x); r[1] = (short)f2bf(lo.y);
    r[2] = (short)f2bf(lo.z); r[3] = (short)f2bf(lo.w);
    r[4] = (short)f2bf(hi.x); r[5] = (short)f2bf(hi.y);
    r[6] = (short)f2bf(hi.z); r[7] = (short)f2bf(hi.w);
    return r;
}

// ---------------- K0: w1 repack f32->bf16; sin/cos table; zero gacc8/cnt/mean ----------
__global__ void k0_prep(const float* __restrict__ w1, unsigned short* __restrict__ w1c,
                        float* __restrict__ gacc8, float* __restrict__ sintab,
                        float* __restrict__ costab, float* __restrict__ out,
                        int* __restrict__ cnt) {
    int o = blockIdx.x * 256 + threadIdx.x;   // 72*256 = 18432 = 9*64*32
    int c0  = o & 31;
    int c1  = (o >> 5) & 63;
    int tap = o >> 11;                        // 0..8
    w1c[o] = f2bf(w1[(c1 * 32 + c0) * 9 + tap]);
    if (o < 10240) {                          // 40 f x 256 w phase table + gacc8 zero
        int f = o >> 8, w = o & 255;
        float ph = 6.283185307179586f * (float)(f + 1) * (1.0f / 255.0f) * (float)w;
        sintab[o] = sinf(ph);
        costab[o] = cosf(ph);
        gacc8[o] = 0.0f;                      // 8 replicas x 1280 = 10240 floats
    }
    if (o == 0) { out[51200] = 0.0f; cnt[0] = 0; }
}

// ---------------- K1: fused conv0(relu) + conv1(relu) via bf16 MFMA -> x (bf16) --------
// grid (4 jt, 9 it, 32 b), block 256 (4 waves).
// conv0 is now sliding-window: one output ROW per thread (pg 0..5), float4 LDS reads
// with register carry-over: ~54 ds_read_b128/thread replaces 450 ds_read_b32 (the old
// version was LDS-issue-bound: ~10.4k LDS-pipe cycles/block).
__global__ __launch_bounds__(256) void k1_conv(
        const float* __restrict__ inp, const float* __restrict__ w0,
        const float* __restrict__ b0, const unsigned short* __restrict__ w1c,
        const float* __restrict__ b1, unsigned short* __restrict__ xbf) {
    __shared__ __align__(16) char smem[33856];
    float* ins = (float*)smem;                              // 544*4  = 2176 B
    unsigned short* y0T = (unsigned short*)(smem + 2176);   // 396*40*2 = 31680 B
    unsigned short* stg = (unsigned short*)smem;            // epilogue reuse: 32768 B

    const int jt = blockIdx.x;        // j0 = 64*jt
    const int it = blockIdx.y;        // i0 = 4*it
    const int b  = blockIdx.z;
    const int i0 = it * 4;
    const int j0 = jt * 64;
    const int tid = threadIdx.x;

    // ---- stage input rows i0..i0+7, cols j0..j0+67 ----
    for (int s = tid; s < 544; s += 256) {
        int r = s / 68, c = s - r * 68;
        int gc = j0 + c;
        ins[s] = (gc < WW) ? inp[(b * HH + i0 + r) * WW + gc] : 0.0f;
    }
    __syncthreads();

    // ---- conv0 -> y0T bf16 [pos][c0 (pad 40)], sliding-window float4 ----
    {
        const int c0 = tid & 31;
        const int pg = tid >> 5;      // 0..7; rows 0..5 active
        if (pg < 6) {
            float wreg[9];
            #pragma unroll
            for (int k = 0; k < 9; ++k) wreg[k] = w0[c0 * 9 + k];
            const float bias = b0[c0];
            const float4* rp0 = (const float4*)(ins + (pg    ) * 68);  // 68 = 17 float4
            const float4* rp1 = (const float4*)(ins + (pg + 1) * 68);
            const float4* rp2 = (const float4*)(ins + (pg + 2) * 68);
            unsigned short* yrow = y0T + pg * 66 * 40 + c0;
            float4 a0 = rp0[0], a1 = rp1[0], a2 = rp2[0];
            #pragma unroll 2
            for (int ch = 0; ch < 8; ++ch) {                // cols 8ch..8ch+7
                float4 b0v = rp0[2 * ch + 1], c0v = rp0[2 * ch + 2];
                float4 b1v = rp1[2 * ch + 1], c1v = rp1[2 * ch + 2];
                float4 b2v = rp2[2 * ch + 1], c2v = rp2[2 * ch + 2];
                float r0[12] = {a0.x,a0.y,a0.z,a0.w,b0v.x,b0v.y,b0v.z,b0v.w,c0v.x,c0v.y,c0v.z,c0v.w};
                float r1[12] = {a1.x,a1.y,a1.z,a1.w,b1v.x,b1v.y,b1v.z,b1v.w,c1v.x,c1v.y,c1v.z,c1v.w};
                float r2[12] = {a2.x,a2.y,a2.z,a2.w,b2v.x,b2v.y,b2v.z,b2v.w,c2v.x,c2v.y,c2v.z,c2v.w};
                #pragma unroll
                for (int t = 0; t < 8; ++t) {
                    int col = ch * 8 + t;
                    float a = bias;
                    #pragma unroll
                    for (int kj = 0; kj < 3; ++kj) {
                        a = fmaf(r0[t + kj], wreg[kj],     a);
                        a = fmaf(r1[t + kj], wreg[3 + kj], a);
                        a = fmaf(r2[t + kj], wreg[6 + kj], a);
                    }
                    float v = (j0 + col < 254) ? fmaxf(a, 0.0f) : 0.0f;
                    yrow[col * 40] = f2bf(v);
                }
                a0 = c0v; a1 = c1v; a2 = c2v;               // carry floats 8ch+8..11
            }
            // tail cols 64,65: carried a? = floats 64..67
            {
                float t0[4] = {a0.x, a0.y, a0.z, a0.w};
                float t1[4] = {a1.x, a1.y, a1.z, a1.w};
                float t2[4] = {a2.x, a2.y, a2.z, a2.w};
                #pragma unroll
                for (int t = 0; t < 2; ++t) {
                    int col = 64 + t;
                    float a = bias;
                    #pragma unroll
                    for (int kj = 0; kj < 3; ++kj) {
                        a = fmaf(t0[t + kj], wreg[kj],     a);
                        a = fmaf(t1[t + kj], wreg[3 + kj], a);
                        a = fmaf(t2[t + kj], wreg[6 + kj], a);
                    }
                    float v = (j0 + col < 254) ? fmaxf(a, 0.0f) : 0.0f;
                    yrow[col * 40] = f2bf(v);
                }
            }
        }
    }
    __syncthreads();

    // ---- conv1: 9 tap-GEMMs, K=32(c0). A = w1c (global, L2-hot), B = y0T (LDS) ----
    const int w    = tid >> 6;        // wave id -> output row i0+w
    const int lane = tid & 63;
    const int l15  = lane & 15;
    const int quad = lane >> 4;

    float biasr[4][4];                // [mt][reg]
    #pragma unroll
    for (int mt = 0; mt < 4; ++mt)
        #pragma unroll
        for (int rg = 0; rg < 4; ++rg)
            biasr[mt][rg] = b1[mt * 16 + quad * 4 + rg];

    f32x4 acc[4][4];                  // [mt(ch)][nt(pos)]
    #pragma unroll
    for (int mt = 0; mt < 4; ++mt)
        #pragma unroll
        for (int nt = 0; nt < 4; ++nt)
            acc[mt][nt] = (f32x4){0.f, 0.f, 0.f, 0.f};

    #pragma unroll
    for (int ki = 0; ki < 3; ++ki) {
        #pragma unroll
        for (int kj = 0; kj < 3; ++kj) {
            const int tap = ki * 3 + kj;
            bf16x8 af[4], bfr[4];
            #pragma unroll
            for (int mt = 0; mt < 4; ++mt)   // A[m=c1][k=c0]
                af[mt] = *(const bf16x8*)(w1c + ((tap * 64 + mt * 16 + l15) * 32 + quad * 8));
            #pragma unroll
            for (int nt = 0; nt < 4; ++nt)   // B[k=c0][n=pos]
                bfr[nt] = *(const bf16x8*)(y0T + (((w + ki) * 66 + nt * 16 + l15 + kj) * 40 + quad * 8));
            #pragma unroll
            for (int mt = 0; mt < 4; ++mt)
                #pragma unroll
                for (int nt = 0; nt < 4; ++nt)
                    acc[mt][nt] = __builtin_amdgcn_mfma_f32_16x16x32_bf16(
                        af[mt], bfr[nt], acc[mt][nt], 0, 0, 0);
        }
    }

    // ---- epilogue: relu(x+b1) -> LDS tile [c1][w][j] (rotated), coalesced copy-out ----
    __syncthreads();                  // all waves done reading y0T before aliasing as stg
    #pragma unroll
    for (int mt = 0; mt < 4; ++mt)
        #pragma unroll
        for (int nt = 0; nt < 4; ++nt)
            #pragma unroll
            for (int rg = 0; rg < 4; ++rg) {
                int c1 = mt * 16 + quad * 4 + rg;
                int j  = nt * 16 + l15;
                int jr = (j + (((c1 >> 2) & 3) << 4)) & 63;
                float v = fmaxf(acc[mt][nt][rg] + biasr[mt][rg], 0.0f);
                stg[(c1 * 4 + w) * 64 + jr] = f2bf(v);
            }
    __syncthreads();

    const int limit = (j0 + 64 <= W1N) ? 64 : (W1N - j0);   // 64, or 60 at jt==3
    for (int it2 = 0; it2 < 16; ++it2) {
        int cc = it2 * 256 + tid;     // 0..4095
        int e  = cc * 4;              // element index in [c1][w][j]
        int c1 = e >> 8;
        int w2 = (e >> 6) & 3;
        int jb = e & 63;
        if (jb < limit) {
            int jr = (jb + (((c1 >> 2) & 3) << 4)) & 63;
            *(uint2*)(xbf + (size_t)b * KCNN + (c1 * H1N + i0 + w2) * W1N + j0 + jb) =
                *(const uint2*)(stg + (c1 * 4 + w2) * 64 + jr);
        }
    }
}

// ---------------- K2: barrier-free MFMA split-K GEMM -> 8-replica atomic gacc ----------
// 756 blocks x 4 waves. Replica gacc8[blockIdx&7][1280] splits the old 756-way per-line
// atomic contention (968K atomics into 40 cache lines) 8 ways. Last-block-done pattern
// (device atomic counter) computes gates = sigmoid(sum+br) and the wtd_mean inline,
// eliminating the k3 dispatch.
__global__ __launch_bounds__(256) void k2_gemm(
        const unsigned short* __restrict__ xbf, const float* __restrict__ wr,
        float* __restrict__ gacc8, const float* __restrict__ br,
        float* __restrict__ gates, float* __restrict__ out, int* __restrict__ cnt) {
    __shared__ float red[4][32][41];  // wave-partials, stride 41 breaks 4-way conflicts
    __shared__ float wsum[4];
    __shared__ int lastflag;

    const int tid  = threadIdx.x;
    const int wv   = tid >> 6;
    const int lane = tid & 63;
    const int l15  = lane & 15;
    const int quad = lane >> 4;
    const size_t kw = (size_t)(blockIdx.x * 4 + wv) * KPW;

    const unsigned short* ap0 = xbf + (size_t)l15 * KCNN + kw + quad * 8;
    const unsigned short* ap1 = ap0 + (size_t)16 * KCNN;
    const float* bp0 = wr + (size_t)l15 * KCNN + kw + quad * 8;
    const float* bp1 = bp0 + (size_t)16 * KCNN;
    const bool v2 = (l15 < 8);
    const float* bp2 = bp0 + (size_t)32 * KCNN;   // only dereferenced when v2

    f32x4 acc[2][3];
    #pragma unroll
    for (int mt = 0; mt < 2; ++mt)
        #pragma unroll
        for (int nt = 0; nt < 3; ++nt)
            acc[mt][nt] = (f32x4){0.f, 0.f, 0.f, 0.f};

    const float4 fz = {0.f, 0.f, 0.f, 0.f};
    bf16x8 a0c, a1c, a0n, a1n;
    float4 bw[3][2], bwn[3][2];

    a0c = *(const bf16x8*)ap0;
    a1c = *(const bf16x8*)ap1;
    bw[0][0] = *(const float4*)bp0; bw[0][1] = *(const float4*)(bp0 + 4);
    bw[1][0] = *(const float4*)bp1; bw[1][1] = *(const float4*)(bp1 + 4);
    if (v2) { bw[2][0] = *(const float4*)bp2; bw[2][1] = *(const float4*)(bp2 + 4); }
    else    { bw[2][0] = fz; bw[2][1] = fz; }

    for (int c = 0; c < 6; ++c) {
        if (c < 5) {                  // issue next chunk's loads; overlap with MFMA below
            const int o2 = (c + 1) * 32;
            a0n = *(const bf16x8*)(ap0 + o2);
            a1n = *(const bf16x8*)(ap1 + o2);
            bwn[0][0] = *(const float4*)(bp0 + o2); bwn[0][1] = *(const float4*)(bp0 + o2 + 4);
            bwn[1][0] = *(const float4*)(bp1 + o2); bwn[1][1] = *(const float4*)(bp1 + o2 + 4);
            if (v2) { bwn[2][0] = *(const float4*)(bp2 + o2); bwn[2][1] = *(const float4*)(bp2 + o2 + 4); }
            else    { bwn[2][0] = fz; bwn[2][1] = fz; }
        }
        #pragma unroll
        for (int nt = 0; nt < 3; ++nt) {
            bf16x8 bfrag = packbf(bw[nt][0], bw[nt][1]);
            acc[0][nt] = __builtin_amdgcn_mfma_f32_16x16x32_bf16(a0c, bfrag, acc[0][nt], 0, 0, 0);
            acc[1][nt] = __builtin_amdgcn_mfma_f32_16x16x32_bf16(a1c, bfrag, acc[1][nt], 0, 0, 0);
        }
        if (c < 5) {
            a0c = a0n; a1c = a1n;
            #pragma unroll
            for (int nt = 0; nt < 3; ++nt) { bw[nt][0] = bwn[nt][0]; bw[nt][1] = bwn[nt][1]; }
        }
    }

    // ---- reduce 4 waves via LDS, then replica atomics ----
    #pragma unroll
    for (int mt = 0; mt < 2; ++mt)
        #pragma unroll
        for (int nt = 0; nt < 3; ++nt)
            #pragma unroll
            for (int rg = 0; rg < 4; ++rg) {
                int bb = mt * 16 + quad * 4 + rg;
                int ff = nt * 16 + l15;
                if (ff < NF) red[wv][bb][ff] = acc[mt][nt][rg];
            }
    __syncthreads();
    float* myg = gacc8 + (size_t)(blockIdx.x & 7) * 1280;
    for (int p = tid; p < 1280; p += 256) {
        int bb = p / 40, ff = p - bb * 40;
        float s = 0.0f;
        #pragma unroll
        for (int w = 0; w < 4; ++w) s += red[w][bb][ff];
        atomicAdd(myg + p, s);
    }

    // ---- last-block-done: gates + wtd_mean (replaces k3 dispatch) ----
    __threadfence();
    __syncthreads();
    if (tid == 0) lastflag = (atomicAdd(cnt, 1) == NBLK2 - 1) ? 1 : 0;
    __syncthreads();
    if (lastflag) {
        float c = 0.0f;
        for (int p = tid; p < 1280; p += 256) {
            float s = 0.0f;
            #pragma unroll
            for (int r = 0; r < 8; ++r)
                s += atomicAdd(gacc8 + r * 1280 + p, 0.0f);   // coherent read of replica sums
            int f = p % 40;
            float g = 1.0f / (1.0f + __expf(-(s + br[f])));
            gates[p] = g;
            c += g * (2.0f * (float)(f + 1)) * (1.0f / 1280.0f);
        }
        #pragma unroll
        for (int off = 32; off >= 1; off >>= 1) c += __shfl_down(c, off, 64);
        if ((tid & 63) == 0) wsum[tid >> 6] = c;
        __syncthreads();
        if (tid == 0) out[51200] = wsum[0] + wsum[1] + wsum[2] + wsum[3];
    }
}

// ---------------- K4: feats (inline) -> table-driven sin/cos projection -> mods --------
__global__ __launch_bounds__(320) void k4_mods(
        const float* __restrict__ inp, const float* __restrict__ sintab,
        const float* __restrict__ costab, const float* __restrict__ wf,
        const float* __restrict__ bfp, const float* __restrict__ gates,
        float* __restrict__ out) {
    const int f = blockIdx.x, b = blockIdx.y;
    const int tid = threadIdx.x;
    const int h  = tid >> 3;
    const int wl = tid & 7;
    float wfv[5];
    #pragma unroll
    for (int t = 0; t < 5; ++t) wfv[t] = wf[t];
    const float bias = bfp[0];
    const float* row  = inp + (b * HH + h) * WW;
    const float* srow = sintab + f * 256;
    const float* crow = costab + f * 256;
    float sa = 0.0f, ca = 0.0f;
    for (int m = 0; m < 32; ++m) {
        int w = wl + 8 * m;
        float feat = bias;
        #pragma unroll
        for (int d = -2; d <= 2; ++d) {
            int wc = w + d;
            if (wc >= 0 && wc < WW) feat = fmaf(row[wc], wfv[d + 2], feat);
        }
        sa = fmaf(srow[w], feat, sa);
        ca = fmaf(crow[w], feat, ca);
    }
    #pragma unroll
    for (int off = 4; off >= 1; off >>= 1) {
        sa += __shfl_xor(sa, off, 8);
        ca += __shfl_xor(ca, off, 8);
    }
    if (wl == 0) {
        float mag = sqrtf(sa * sa + ca * ca) * (1.0f / 256.0f);
        out[b * 1600 + f * 40 + h] = mag * gates[b * 40 + f];
    }
}

extern "C" void kernel_launch(void* const* d_in, const int* in_sizes, int n_in,
                              void* d_out, int out_size, void* d_ws, size_t ws_size,
                              hipStream_t stream) {
    const float* inp = (const float*)d_in[0];
    const float* w0  = (const float*)d_in[1];
    const float* b0  = (const float*)d_in[2];
    const float* w1  = (const float*)d_in[3];
    const float* b1  = (const float*)d_in[4];
    const float* wf  = (const float*)d_in[5];
    const float* bf_ = (const float*)d_in[6];
    const float* wr  = (const float*)d_in[7];
    const float* br  = (const float*)d_in[8];
    float* out = (float*)d_out;

    char* ws = (char*)d_ws;
    unsigned short* xbf = (unsigned short*)ws;               // 37,158,912 B
    unsigned short* w1c = (unsigned short*)(ws + 37158912);  // 36,864 B
    float* gacc8  = (float*)(ws + 37195776);                 // 8*1280*4 = 40,960 B
    float* gates  = (float*)(ws + 37236736);                 // 5,120 B
    float* sintab = (float*)(ws + 37241856);                 // 40,960 B
    float* costab = (float*)(ws + 37282816);                 // 40,960 B
    int*   cnt    = (int*)(ws + 37323776);                   // 4 B

    k0_prep<<<72, 256, 0, stream>>>(w1, w1c, gacc8, sintab, costab, out, cnt);
    k1_conv<<<dim3(4, 9, 32), 256, 0, stream>>>(inp, w0, b0, w1c, b1, xbf);
    k2_gemm<<<756, 256, 0, stream>>>(xbf, wr, gacc8, br, gates, out, cnt);
    k4_mods<<<dim3(40, 32), 320, 0, stream>>>(inp, sintab, costab, wf, bf_, gates, out);
}

// Round 4
// 219.075 us; speedup vs baseline: 1.5287x; 1.5287x over previous
//
#include <hip/hip_runtime.h>
#include <hip/hip_bf16.h>
#include <math.h>

// Problem constants
#define BB   32
#define HH   40
#define WW   256
#define NF   40          // FREQ
#define H1N  36
#define W1N  252
#define KCNN 580608      // 64*36*252
#define KPW  192         // k per wave (6 chunks x 32); 3024 waves * 192 == KCNN exactly

typedef __attribute__((ext_vector_type(8))) short bf16x8;   // 8 bf16 = 4 VGPRs
typedef __attribute__((ext_vector_type(4))) float f32x4;    // MFMA C/D

static __device__ __forceinline__ unsigned short f2bf(float v) {
    __hip_bfloat16 h = __float2bfloat16(v);
    return *(unsigned short*)&h;
}

static __device__ __forceinline__ bf16x8 packbf(float4 lo, float4 hi) {
    bf16x8 r;
    r[0] = (short)f2bf(lo.x); r[1] = (short)f2bf(lo.y);
    r[2] = (short)f2bf(lo.z); r[3] = (short)f2bf(lo.w);
    r[4] = (short)f2bf(hi.x); r[5] = (short)f2bf(hi.y);
    r[6] = (short)f2bf(hi.z); r[7] = (short)f2bf(hi.w);
    return r;
}

// ---------------- K0: w1 repack f32->bf16; sin/cos table; zero gacc8/mean ----------
__global__ void k0_prep(const float* __restrict__ w1, unsigned short* __restrict__ w1c,
                        float* __restrict__ gacc8, float* __restrict__ sintab,
                        float* __restrict__ costab, float* __restrict__ out) {
    int o = blockIdx.x * 256 + threadIdx.x;   // 72*256 = 18432 = 9*64*32
    int c0  = o & 31;
    int c1  = (o >> 5) & 63;
    int tap = o >> 11;                        // 0..8
    w1c[o] = f2bf(w1[(c1 * 32 + c0) * 9 + tap]);
    if (o < 10240) {                          // 40 f x 256 w phase table + gacc8 zero
        int f = o >> 8, w = o & 255;
        float ph = 6.283185307179586f * (float)(f + 1) * (1.0f / 255.0f) * (float)w;
        sintab[o] = sinf(ph);
        costab[o] = cosf(ph);
        gacc8[o] = 0.0f;                      // 8 replicas x 1280 = 10240 floats
    }
    if (o == 0) out[51200] = 0.0f;
}

// ---------------- K1: fused conv0(relu) + conv1(relu) via bf16 MFMA -> x (bf16) --------
// grid (4 jt, 9 it, 32 b), block 256 (4 waves).
// conv0 is sliding-window: one output ROW per thread (pg 0..5), float4 LDS reads with
// register carry-over (~54 ds_read_b128/thread vs 450 ds_read_b32 originally).
__global__ __launch_bounds__(256) void k1_conv(
        const float* __restrict__ inp, const float* __restrict__ w0,
        const float* __restrict__ b0, const unsigned short* __restrict__ w1c,
        const float* __restrict__ b1, unsigned short* __restrict__ xbf) {
    __shared__ __align__(16) char smem[33856];
    float* ins = (float*)smem;                              // 544*4  = 2176 B
    unsigned short* y0T = (unsigned short*)(smem + 2176);   // 396*40*2 = 31680 B
    unsigned short* stg = (unsigned short*)smem;            // epilogue reuse: 32768 B

    const int jt = blockIdx.x;        // j0 = 64*jt
    const int it = blockIdx.y;        // i0 = 4*it
    const int b  = blockIdx.z;
    const int i0 = it * 4;
    const int j0 = jt * 64;
    const int tid = threadIdx.x;

    // ---- stage input rows i0..i0+7, cols j0..j0+67 ----
    for (int s = tid; s < 544; s += 256) {
        int r = s / 68, c = s - r * 68;
        int gc = j0 + c;
        ins[s] = (gc < WW) ? inp[(b * HH + i0 + r) * WW + gc] : 0.0f;
    }
    __syncthreads();

    // ---- conv0 -> y0T bf16 [pos][c0 (pad 40)], sliding-window float4 ----
    {
        const int c0 = tid & 31;
        const int pg = tid >> 5;      // 0..7; rows 0..5 active
        if (pg < 6) {
            float wreg[9];
            #pragma unroll
            for (int k = 0; k < 9; ++k) wreg[k] = w0[c0 * 9 + k];
            const float bias = b0[c0];
            const float4* rp0 = (const float4*)(ins + (pg    ) * 68);  // 68 = 17 float4
            const float4* rp1 = (const float4*)(ins + (pg + 1) * 68);
            const float4* rp2 = (const float4*)(ins + (pg + 2) * 68);
            unsigned short* yrow = y0T + pg * 66 * 40 + c0;
            float4 a0 = rp0[0], a1 = rp1[0], a2 = rp2[0];
            #pragma unroll 2
            for (int ch = 0; ch < 8; ++ch) {                // cols 8ch..8ch+7
                float4 b0v = rp0[2 * ch + 1], c0v = rp0[2 * ch + 2];
                float4 b1v = rp1[2 * ch + 1], c1v = rp1[2 * ch + 2];
                float4 b2v = rp2[2 * ch + 1], c2v = rp2[2 * ch + 2];
                float r0[12] = {a0.x,a0.y,a0.z,a0.w,b0v.x,b0v.y,b0v.z,b0v.w,c0v.x,c0v.y,c0v.z,c0v.w};
                float r1[12] = {a1.x,a1.y,a1.z,a1.w,b1v.x,b1v.y,b1v.z,b1v.w,c1v.x,c1v.y,c1v.z,c1v.w};
                float r2[12] = {a2.x,a2.y,a2.z,a2.w,b2v.x,b2v.y,b2v.z,b2v.w,c2v.x,c2v.y,c2v.z,c2v.w};
                #pragma unroll
                for (int t = 0; t < 8; ++t) {
                    int col = ch * 8 + t;
                    float a = bias;
                    #pragma unroll
                    for (int kj = 0; kj < 3; ++kj) {
                        a = fmaf(r0[t + kj], wreg[kj],     a);
                        a = fmaf(r1[t + kj], wreg[3 + kj], a);
                        a = fmaf(r2[t + kj], wreg[6 + kj], a);
                    }
                    float v = (j0 + col < 254) ? fmaxf(a, 0.0f) : 0.0f;
                    yrow[col * 40] = f2bf(v);
                }
                a0 = c0v; a1 = c1v; a2 = c2v;               // carry floats 8ch+8..11
            }
            // tail cols 64,65: carried a? = floats 64..67
            {
                float t0[4] = {a0.x, a0.y, a0.z, a0.w};
                float t1[4] = {a1.x, a1.y, a1.z, a1.w};
                float t2[4] = {a2.x, a2.y, a2.z, a2.w};
                #pragma unroll
                for (int t = 0; t < 2; ++t) {
                    int col = 64 + t;
                    float a = bias;
                    #pragma unroll
                    for (int kj = 0; kj < 3; ++kj) {
                        a = fmaf(t0[t + kj], wreg[kj],     a);
                        a = fmaf(t1[t + kj], wreg[3 + kj], a);
                        a = fmaf(t2[t + kj], wreg[6 + kj], a);
                    }
                    float v = (j0 + col < 254) ? fmaxf(a, 0.0f) : 0.0f;
                    yrow[col * 40] = f2bf(v);
                }
            }
        }
    }
    __syncthreads();

    // ---- conv1: 9 tap-GEMMs, K=32(c0). A = w1c (global, L2-hot), B = y0T (LDS) ----
    const int w    = tid >> 6;        // wave id -> output row i0+w
    const int lane = tid & 63;
    const int l15  = lane & 15;
    const int quad = lane >> 4;

    float biasr[4][4];                // [mt][reg]
    #pragma unroll
    for (int mt = 0; mt < 4; ++mt)
        #pragma unroll
        for (int rg = 0; rg < 4; ++rg)
            biasr[mt][rg] = b1[mt * 16 + quad * 4 + rg];

    f32x4 acc[4][4];                  // [mt(ch)][nt(pos)]
    #pragma unroll
    for (int mt = 0; mt < 4; ++mt)
        #pragma unroll
        for (int nt = 0; nt < 4; ++nt)
            acc[mt][nt] = (f32x4){0.f, 0.f, 0.f, 0.f};

    #pragma unroll
    for (int ki = 0; ki < 3; ++ki) {
        #pragma unroll
        for (int kj = 0; kj < 3; ++kj) {
            const int tap = ki * 3 + kj;
            bf16x8 af[4], bfr[4];
            #pragma unroll
            for (int mt = 0; mt < 4; ++mt)   // A[m=c1][k=c0]
                af[mt] = *(const bf16x8*)(w1c + ((tap * 64 + mt * 16 + l15) * 32 + quad * 8));
            #pragma unroll
            for (int nt = 0; nt < 4; ++nt)   // B[k=c0][n=pos]
                bfr[nt] = *(const bf16x8*)(y0T + (((w + ki) * 66 + nt * 16 + l15 + kj) * 40 + quad * 8));
            #pragma unroll
            for (int mt = 0; mt < 4; ++mt)
                #pragma unroll
                for (int nt = 0; nt < 4; ++nt)
                    acc[mt][nt] = __builtin_amdgcn_mfma_f32_16x16x32_bf16(
                        af[mt], bfr[nt], acc[mt][nt], 0, 0, 0);
        }
    }

    // ---- epilogue: relu(x+b1) -> LDS tile [c1][w][j] (rotated), coalesced copy-out ----
    __syncthreads();                  // all waves done reading y0T before aliasing as stg
    #pragma unroll
    for (int mt = 0; mt < 4; ++mt)
        #pragma unroll
        for (int nt = 0; nt < 4; ++nt)
            #pragma unroll
            for (int rg = 0; rg < 4; ++rg) {
                int c1 = mt * 16 + quad * 4 + rg;
                int j  = nt * 16 + l15;
                int jr = (j + (((c1 >> 2) & 3) << 4)) & 63;
                float v = fmaxf(acc[mt][nt][rg] + biasr[mt][rg], 0.0f);
                stg[(c1 * 4 + w) * 64 + jr] = f2bf(v);
            }
    __syncthreads();

    const int limit = (j0 + 64 <= W1N) ? 64 : (W1N - j0);   // 64, or 60 at jt==3
    for (int it2 = 0; it2 < 16; ++it2) {
        int cc = it2 * 256 + tid;     // 0..4095
        int e  = cc * 4;              // element index in [c1][w][j]
        int c1 = e >> 8;
        int w2 = (e >> 6) & 3;
        int jb = e & 63;
        if (jb < limit) {
            int jr = (jb + (((c1 >> 2) & 3) << 4)) & 63;
            *(uint2*)(xbf + (size_t)b * KCNN + (c1 * H1N + i0 + w2) * W1N + j0 + jb) =
                *(const uint2*)(stg + (c1 * 4 + w2) * 64 + jr);
        }
    }
}

// ---------------- K2: barrier-free MFMA split-K GEMM -> 8-replica atomic gacc ----------
// 756 blocks x 4 waves (~12 waves/CU, even spread). Each wave owns a private 192-k
// slice; per 32-k chunk: 2 A-loads (x bf16) + 6 B-loads (wr f32->bf16) + 6 MFMA.
// No __syncthreads in the k-loop; 2-deep register pipeline. NO device fence (the
// round-2 last-block fusion's __threadfence caused 756 L2 writeback-invalidates ->
// 165 us of memory-system stall; reverted).
__global__ __launch_bounds__(256) void k2_gemm(
        const unsigned short* __restrict__ xbf, const float* __restrict__ wr,
        float* __restrict__ gacc8) {
    __shared__ float red[4][32][41];  // wave-partials, stride 41 breaks 4-way conflicts

    const int tid  = threadIdx.x;
    const int wv   = tid >> 6;
    const int lane = tid & 63;
    const int l15  = lane & 15;
    const int quad = lane >> 4;
    const size_t kw = (size_t)(blockIdx.x * 4 + wv) * KPW;

    const unsigned short* ap0 = xbf + (size_t)l15 * KCNN + kw + quad * 8;
    const unsigned short* ap1 = ap0 + (size_t)16 * KCNN;
    const float* bp0 = wr + (size_t)l15 * KCNN + kw + quad * 8;
    const float* bp1 = bp0 + (size_t)16 * KCNN;
    const bool v2 = (l15 < 8);
    const float* bp2 = bp0 + (size_t)32 * KCNN;   // only dereferenced when v2

    f32x4 acc[2][3];
    #pragma unroll
    for (int mt = 0; mt < 2; ++mt)
        #pragma unroll
        for (int nt = 0; nt < 3; ++nt)
            acc[mt][nt] = (f32x4){0.f, 0.f, 0.f, 0.f};

    const float4 fz = {0.f, 0.f, 0.f, 0.f};
    bf16x8 a0c, a1c, a0n, a1n;
    float4 bw[3][2], bwn[3][2];

    a0c = *(const bf16x8*)ap0;
    a1c = *(const bf16x8*)ap1;
    bw[0][0] = *(const float4*)bp0; bw[0][1] = *(const float4*)(bp0 + 4);
    bw[1][0] = *(const float4*)bp1; bw[1][1] = *(const float4*)(bp1 + 4);
    if (v2) { bw[2][0] = *(const float4*)bp2; bw[2][1] = *(const float4*)(bp2 + 4); }
    else    { bw[2][0] = fz; bw[2][1] = fz; }

    for (int c = 0; c < 6; ++c) {
        if (c < 5) {                  // issue next chunk's loads; overlap with MFMA below
            const int o2 = (c + 1) * 32;
            a0n = *(const bf16x8*)(ap0 + o2);
            a1n = *(const bf16x8*)(ap1 + o2);
            bwn[0][0] = *(const float4*)(bp0 + o2); bwn[0][1] = *(const float4*)(bp0 + o2 + 4);
            bwn[1][0] = *(const float4*)(bp1 + o2); bwn[1][1] = *(const float4*)(bp1 + o2 + 4);
            if (v2) { bwn[2][0] = *(const float4*)(bp2 + o2); bwn[2][1] = *(const float4*)(bp2 + o2 + 4); }
            else    { bwn[2][0] = fz; bwn[2][1] = fz; }
        }
        #pragma unroll
        for (int nt = 0; nt < 3; ++nt) {
            bf16x8 bfrag = packbf(bw[nt][0], bw[nt][1]);
            acc[0][nt] = __builtin_amdgcn_mfma_f32_16x16x32_bf16(a0c, bfrag, acc[0][nt], 0, 0, 0);
            acc[1][nt] = __builtin_amdgcn_mfma_f32_16x16x32_bf16(a1c, bfrag, acc[1][nt], 0, 0, 0);
        }
        if (c < 5) {
            a0c = a0n; a1c = a1n;
            #pragma unroll
            for (int nt = 0; nt < 3; ++nt) { bw[nt][0] = bwn[nt][0]; bw[nt][1] = bwn[nt][1]; }
        }
    }

    // ---- reduce 4 waves via LDS, then replica atomics ----
    #pragma unroll
    for (int mt = 0; mt < 2; ++mt)
        #pragma unroll
        for (int nt = 0; nt < 3; ++nt)
            #pragma unroll
            for (int rg = 0; rg < 4; ++rg) {
                int bb = mt * 16 + quad * 4 + rg;
                int ff = nt * 16 + l15;
                if (ff < NF) red[wv][bb][ff] = acc[mt][nt][rg];
            }
    __syncthreads();
    float* myg = gacc8 + (size_t)(blockIdx.x & 7) * 1280;
    for (int p = tid; p < 1280; p += 256) {
        int bb = p / 40, ff = p - bb * 40;
        float s = 0.0f;
        #pragma unroll
        for (int w = 0; w < 4; ++w) s += red[w][bb][ff];
        atomicAdd(myg + p, s);
    }
}

// ---------------- K3: gates = sigmoid(sum(gacc8) + br); wave-reduced wtd_mean ----------
__global__ void k3_gates(const float* __restrict__ gacc8, const float* __restrict__ br,
                         float* __restrict__ gates, float* __restrict__ out) {
    int p = blockIdx.x * 64 + threadIdx.x;    // 20 blocks -> 1280
    int f = p % 40;
    float s = 0.0f;
    #pragma unroll
    for (int r = 0; r < 8; ++r) s += gacc8[r * 1280 + p];
    float g = 1.0f / (1.0f + __expf(-(s + br[f])));
    gates[p] = g;
    float c = g * (2.0f * (float)(f + 1)) * (1.0f / 1280.0f);
    #pragma unroll
    for (int off = 32; off >= 1; off >>= 1)   // wave64 reduce -> 1 atomic/wave
        c += __shfl_down(c, off, 64);
    if (threadIdx.x == 0) atomicAdd(out + 51200, c);
}

// ---------------- K4: feats (inline) -> table-driven sin/cos projection -> mods --------
__global__ __launch_bounds__(320) void k4_mods(
        const float* __restrict__ inp, const float* __restrict__ sintab,
        const float* __restrict__ costab, const float* __restrict__ wf,
        const float* __restrict__ bfp, const float* __restrict__ gates,
        float* __restrict__ out) {
    const int f = blockIdx.x, b = blockIdx.y;
    const int tid = threadIdx.x;
    const int h  = tid >> 3;
    const int wl = tid & 7;
    float wfv[5];
    #pragma unroll
    for (int t = 0; t < 5; ++t) wfv[t] = wf[t];
    const float bias = bfp[0];
    const float* row  = inp + (b * HH + h) * WW;
    const float* srow = sintab + f * 256;
    const float* crow = costab + f * 256;
    float sa = 0.0f, ca = 0.0f;
    for (int m = 0; m < 32; ++m) {
        int w = wl + 8 * m;
        float feat = bias;
        #pragma unroll
        for (int d = -2; d <= 2; ++d) {
            int wc = w + d;
            if (wc >= 0 && wc < WW) feat = fmaf(row[wc], wfv[d + 2], feat);
        }
        sa = fmaf(srow[w], feat, sa);
        ca = fmaf(crow[w], feat, ca);
    }
    #pragma unroll
    for (int off = 4; off >= 1; off >>= 1) {
        sa += __shfl_xor(sa, off, 8);
        ca += __shfl_xor(ca, off, 8);
    }
    if (wl == 0) {
        float mag = sqrtf(sa * sa + ca * ca) * (1.0f / 256.0f);
        out[b * 1600 + f * 40 + h] = mag * gates[b * 40 + f];
    }
}

extern "C" void kernel_launch(void* const* d_in, const int* in_sizes, int n_in,
                              void* d_out, int out_size, void* d_ws, size_t ws_size,
                              hipStream_t stream) {
    const float* inp = (const float*)d_in[0];
    const float* w0  = (const float*)d_in[1];
    const float* b0  = (const float*)d_in[2];
    const float* w1  = (const float*)d_in[3];
    const float* b1  = (const float*)d_in[4];
    const float* wf  = (const float*)d_in[5];
    const float* bf_ = (const float*)d_in[6];
    const float* wr  = (const float*)d_in[7];
    const float* br  = (const float*)d_in[8];
    float* out = (float*)d_out;

    char* ws = (char*)d_ws;
    unsigned short* xbf = (unsigned short*)ws;               // 37,158,912 B
    unsigned short* w1c = (unsigned short*)(ws + 37158912);  // 36,864 B
    float* gacc8  = (float*)(ws + 37195776);                 // 8*1280*4 = 40,960 B
    float* gates  = (float*)(ws + 37236736);                 // 5,120 B
    float* sintab = (float*)(ws + 37241856);                 // 40,960 B
    float* costab = (float*)(ws + 37282816);                 // 40,960 B

    k0_prep<<<72, 256, 0, stream>>>(w1, w1c, gacc8, sintab, costab, out);
    k1_conv<<<dim3(4, 9, 32), 256, 0, stream>>>(inp, w0, b0, w1c, b1, xbf);
    k2_gemm<<<756, 256, 0, stream>>>(xbf, wr, gacc8);
    k3_gates<<<20, 64, 0, stream>>>(gacc8, br, gates, out);
    k4_mods<<<dim3(40, 32), 320, 0, stream>>>(inp, sintab, costab, wf, bf_, gates, out);
}